// Round 2
// baseline (146.614 us; speedup 1.0000x reference)
//
#include <hip/hip_runtime.h>
#include <hip/hip_bf16.h>
#include <cstddef>

// Problem constants (match reference)
static constexpr int Bdim = 32;
static constexpr int Edim = 256;
static constexpr int Cdim = 7;
static constexpr int Ddim = 256;

// Precomputed fused tables, 101 rows of 256 floats:
// rows   0..52 : cardP = card_table   @ Wc[   0: 256]
// rows  53..61 : heroP = hero_table   @ Wc[ 256: 512]
// rows  62..70 : actP  = acting_table @ Wc[ 512: 768]
// rows  71..80 : numP  = nump_table   @ Wc[ 768:1024]
// rows  81..82 : WsP   = W_scalar     @ Wc[1024:1280]
// rows  83..91 : WbP   = W_bet        @ Wc[1280:1536]
// rows  92..99 : WaP   = W_action     @ Wc[1536:1792]
// row   100   : biasT = b_combine + b_scalar@Wc[1024:1280]
//                                 + b_bet   @Wc[1280:1536]
//                                 + b_action@Wc[1536:1792]
//               (each bias is a FULL (256,) vector -> full 256-dot each;
//                round-1 bug was projecting only the first 2/9/8 elements)
// g_sums[r]   : row sums of card rows (for LN mean decomposition)
__device__ float g_tabs[101 * Ddim];
__device__ float g_sums[53];

// One block per row (101 blocks x 256 threads). Thread d computes
// g_tabs[r][d] = sum_k src_r[k] * Wc[off + k][d].
// Card rows additionally block-reduce their row sum into g_sums[r].
__global__ __launch_bounds__(256) void precompute_tables(
    const float* __restrict__ card_table,
    const float* __restrict__ hero_table,
    const float* __restrict__ acting_table,
    const float* __restrict__ nump_table,
    const float* __restrict__ W_scalar, const float* __restrict__ b_scalar,
    const float* __restrict__ W_bet,    const float* __restrict__ b_bet,
    const float* __restrict__ W_action, const float* __restrict__ b_action,
    const float* __restrict__ W_combine, const float* __restrict__ b_combine)
{
    const int r = blockIdx.x;
    const int d = threadIdx.x;

    if (r == 100) {
        // fused bias row: b_combine + the three projected (256,)-biases
        const float* biases[3] = { b_scalar, b_bet, b_action };
        float acc = b_combine[d];
        #pragma unroll
        for (int seg = 0; seg < 3; ++seg) {
            const float* src = biases[seg];
            const float* w = W_combine + (size_t)(1024 + seg * 256) * Ddim + d;
            float a0 = 0.f, a1 = 0.f, a2 = 0.f, a3 = 0.f;
            #pragma unroll 8
            for (int k = 0; k < 64; ++k) {
                a0 = fmaf(src[k      ], w[(size_t)(k      ) * Ddim], a0);
                a1 = fmaf(src[k +  64], w[(size_t)(k +  64) * Ddim], a1);
                a2 = fmaf(src[k + 128], w[(size_t)(k + 128) * Ddim], a2);
                a3 = fmaf(src[k + 192], w[(size_t)(k + 192) * Ddim], a3);
            }
            acc += (a0 + a1) + (a2 + a3);
        }
        g_tabs[(size_t)100 * Ddim + d] = acc;
        return;
    }

    const float* srcp;
    int off;
    if      (r <  53) { srcp = card_table   + (size_t)r        * Ddim; off = 0;    }
    else if (r <  62) { srcp = hero_table   + (size_t)(r - 53) * Ddim; off = 256;  }
    else if (r <  71) { srcp = acting_table + (size_t)(r - 62) * Ddim; off = 512;  }
    else if (r <  81) { srcp = nump_table   + (size_t)(r - 71) * Ddim; off = 768;  }
    else if (r <  83) { srcp = W_scalar     + (size_t)(r - 81) * Ddim; off = 1024; }
    else if (r <  92) { srcp = W_bet        + (size_t)(r - 83) * Ddim; off = 1280; }
    else              { srcp = W_action     + (size_t)(r - 92) * Ddim; off = 1536; }

    const float* w = W_combine + (size_t)off * Ddim + d;
    float a0 = 0.f, a1 = 0.f, a2 = 0.f, a3 = 0.f;
    #pragma unroll 8
    for (int k = 0; k < 64; ++k) {
        const float s0 = srcp[k      ];
        const float s1 = srcp[k +  64];
        const float s2 = srcp[k + 128];
        const float s3 = srcp[k + 192];
        a0 = fmaf(s0, w[(size_t)(k      ) * Ddim], a0);
        a1 = fmaf(s1, w[(size_t)(k +  64) * Ddim], a1);
        a2 = fmaf(s2, w[(size_t)(k + 128) * Ddim], a2);
        a3 = fmaf(s3, w[(size_t)(k + 192) * Ddim], a3);
    }
    const float v = (a0 + a1) + (a2 + a3);
    g_tabs[(size_t)r * Ddim + d] = v;

    if (r < 53) {
        // block-reduce the row sum for the mean decomposition
        float t = v;
        #pragma unroll
        for (int o = 32; o > 0; o >>= 1) t += __shfl_xor(t, o, 64);
        __shared__ float ws4[4];
        if ((threadIdx.x & 63) == 0) ws4[threadIdx.x >> 6] = t;
        __syncthreads();
        if (threadIdx.x == 0) g_sums[r] = (ws4[0] + ws4[1]) + (ws4[2] + ws4[3]);
    }
}

__device__ __forceinline__ float4 ld4(const float* p) {
    return *reinterpret_cast<const float4*>(p);
}
__device__ __forceinline__ void add4(float4& a, const float4 b) {
    a.x += b.x; a.y += b.y; a.z += b.z; a.w += b.w;
}
__device__ __forceinline__ void fma4(float4& a, const float s, const float4 b) {
    a.x = fmaf(s, b.x, a.x);
    a.y = fmaf(s, b.y, a.y);
    a.z = fmaf(s, b.z, a.z);
    a.w = fmaf(s, b.w, a.w);
}

// One wave (64 lanes) per event; lane holds d = 4*lane .. 4*lane+3 as float4.
// LN mean decomposed: mean = (rowsum(card) + sum(ctx))/256, so only the
// sum-of-squares needs a per-card butterfly (6 shuffles instead of 12),
// and the epilogue is folded to o = h*A + B per element.
__global__ __launch_bounds__(256) void event_embed(
    const int* __restrict__ card_ids,
    const int* __restrict__ hero_pos,
    const int* __restrict__ acting_pos,
    const int* __restrict__ num_players,
    const int* __restrict__ seq_lengths,
    const float* __restrict__ scalars,
    const float* __restrict__ bets,
    const float* __restrict__ action,
    const float* __restrict__ source_table,
    const float* __restrict__ ln_gamma,
    const float* __restrict__ ln_beta,
    float* __restrict__ out_emb,
    float* __restrict__ out_mask)
{
    const int wave = threadIdx.x >> 6;
    const int lane = threadIdx.x & 63;
    const int g = (blockIdx.x << 2) + wave;   // event index in [0, B*E)
    const int b = g >> 8;                     // E = 256
    const int e = g & 255;
    const int d0 = lane << 2;

    const float* cardP = g_tabs;
    const float* heroP = cardP + 53 * Ddim;
    const float* actP  = heroP +  9 * Ddim;
    const float* numP  = actP  +  9 * Ddim;
    const float* WsP   = numP  + 10 * Ddim;
    const float* WbP   = WsP   +  2 * Ddim;
    const float* WaP   = WbP   +  9 * Ddim;
    const float* biasT = WaP   +  8 * Ddim;   // row 100 (all biases fused)

    const float maskf = (e < seq_lengths[b]) ? 1.0f : 0.0f;

    // ---- context vector shared by the event's 7 cards ----
    float4 ctx = ld4(biasT + d0);
    add4(ctx, ld4(heroP + (size_t)hero_pos[g]    * Ddim + d0));
    add4(ctx, ld4(actP  + (size_t)acting_pos[g]  * Ddim + d0));
    add4(ctx, ld4(numP  + (size_t)num_players[g] * Ddim + d0));
    const float2 sc = *reinterpret_cast<const float2*>(scalars + (size_t)g * 2);
    fma4(ctx, sc.x, ld4(WsP + d0));
    fma4(ctx, sc.y, ld4(WsP + Ddim + d0));
    #pragma unroll
    for (int j = 0; j < 9; ++j)
        fma4(ctx, bets[(size_t)g * 9 + j], ld4(WbP + j * Ddim + d0));
    const float4 ac0 = ld4(action + (size_t)g * 8);
    const float4 ac1 = ld4(action + (size_t)g * 8 + 4);
    fma4(ctx, ac0.x, ld4(WaP + 0 * Ddim + d0));
    fma4(ctx, ac0.y, ld4(WaP + 1 * Ddim + d0));
    fma4(ctx, ac0.z, ld4(WaP + 2 * Ddim + d0));
    fma4(ctx, ac0.w, ld4(WaP + 3 * Ddim + d0));
    fma4(ctx, ac1.x, ld4(WaP + 4 * Ddim + d0));
    fma4(ctx, ac1.y, ld4(WaP + 5 * Ddim + d0));
    fma4(ctx, ac1.z, ld4(WaP + 6 * Ddim + d0));
    fma4(ctx, ac1.w, ld4(WaP + 7 * Ddim + d0));

    // ---- one reduction for sum(ctx) (feeds mean of every card) ----
    float cs = (ctx.x + ctx.y) + (ctx.z + ctx.w);
    #pragma unroll
    for (int o = 32; o > 0; o >>= 1) cs += __shfl_xor(cs, o, 64);

    const float4 gam = ld4(ln_gamma + d0);
    const float4 bta = ld4(ln_beta + d0);
    const float4 s0v = ld4(source_table + d0);          // source id 0 (cards 0..4)
    const float4 s1v = ld4(source_table + Ddim + d0);   // source id 1 (cards 5..6)
    // (beta + source) * mask, hoisted out of the card loop
    float4 svb0, svb1;
    svb0.x = (bta.x + s0v.x) * maskf; svb0.y = (bta.y + s0v.y) * maskf;
    svb0.z = (bta.z + s0v.z) * maskf; svb0.w = (bta.w + s0v.w) * maskf;
    svb1.x = (bta.x + s1v.x) * maskf; svb1.y = (bta.y + s1v.y) * maskf;
    svb1.z = (bta.z + s1v.z) * maskf; svb1.w = (bta.w + s1v.w) * maskf;

    #pragma unroll
    for (int c = 0; c < Cdim; ++c) {
        const int cid = card_ids[(size_t)g * Cdim + c];
        const float Sc = g_sums[cid];                    // precomputed row sum
        float4 h = ld4(cardP + (size_t)cid * Ddim + d0);
        add4(h, ctx);

        // only sum-of-squares needs the butterfly now
        float sq = h.x * h.x;
        sq = fmaf(h.y, h.y, sq);
        sq = fmaf(h.z, h.z, sq);
        sq = fmaf(h.w, h.w, sq);
        #pragma unroll
        for (int o = 32; o > 0; o >>= 1) sq += __shfl_xor(sq, o, 64);

        const float mean = (Sc + cs) * (1.0f / 256.0f);
        const float var  = fmaf(-mean, mean, sq * (1.0f / 256.0f));
        const float im   = rsqrtf(var + 1e-5f) * maskf;  // mask folded in

        // o = h*A + B,  A = im*gamma,  B = svb*mask - mean*A
        const float4 svb = (c < 5) ? svb0 : svb1;
        float4 A, Bv, o;
        A.x = im * gam.x; A.y = im * gam.y; A.z = im * gam.z; A.w = im * gam.w;
        Bv.x = fmaf(-mean, A.x, svb.x); Bv.y = fmaf(-mean, A.y, svb.y);
        Bv.z = fmaf(-mean, A.z, svb.z); Bv.w = fmaf(-mean, A.w, svb.w);
        o.x = fmaf(h.x, A.x, Bv.x); o.y = fmaf(h.y, A.y, Bv.y);
        o.z = fmaf(h.z, A.z, Bv.z); o.w = fmaf(h.w, A.w, Bv.w);
        *reinterpret_cast<float4*>(out_emb + ((size_t)g * Cdim + c) * Ddim + d0) = o;
    }

    if (lane < Cdim)
        out_mask[(size_t)g * Cdim + lane] = maskf;
}

extern "C" void kernel_launch(void* const* d_in, const int* in_sizes, int n_in,
                              void* d_out, int out_size, void* d_ws, size_t ws_size,
                              hipStream_t stream)
{
    (void)in_sizes; (void)n_in; (void)d_ws; (void)ws_size; (void)out_size;

    const int*   card_ids    = (const int*)d_in[0];
    const int*   hero_pos    = (const int*)d_in[1];
    const int*   acting_pos  = (const int*)d_in[2];
    const int*   num_players = (const int*)d_in[3];
    const int*   seq_lengths = (const int*)d_in[4];
    const float* scalars     = (const float*)d_in[5];
    const float* bets        = (const float*)d_in[6];
    const float* action      = (const float*)d_in[7];
    const float* card_table  = (const float*)d_in[8];
    const float* source_tab  = (const float*)d_in[9];
    const float* hero_table  = (const float*)d_in[10];
    const float* acting_tab  = (const float*)d_in[11];
    const float* nump_table  = (const float*)d_in[12];
    const float* W_scalar    = (const float*)d_in[13];
    const float* b_scalar    = (const float*)d_in[14];
    const float* W_bet       = (const float*)d_in[15];
    const float* b_bet       = (const float*)d_in[16];
    const float* W_action    = (const float*)d_in[17];
    const float* b_action    = (const float*)d_in[18];
    const float* W_combine   = (const float*)d_in[19];
    const float* b_combine   = (const float*)d_in[20];
    const float* ln_gamma    = (const float*)d_in[21];
    const float* ln_beta     = (const float*)d_in[22];

    float* out_emb  = (float*)d_out;
    float* out_mask = out_emb + (size_t)Bdim * Edim * Cdim * Ddim;

    hipLaunchKernelGGL(precompute_tables, dim3(101), dim3(256), 0, stream,
                       card_table, hero_table, acting_tab, nump_table,
                       W_scalar, b_scalar, W_bet, b_bet, W_action, b_action,
                       W_combine, b_combine);

    const int nEvents = Bdim * Edim;             // 8192
    hipLaunchKernelGGL(event_embed, dim3(nEvents / 4), dim3(256), 0, stream,
                       card_ids, hero_pos, acting_pos, num_players, seq_lengths,
                       scalars, bets, action, source_tab,
                       ln_gamma, ln_beta, out_emb, out_mask);
}

// Round 4
// 137.517 us; speedup vs baseline: 1.0662x; 1.0662x over previous
//
#include <hip/hip_runtime.h>
#include <hip/hip_bf16.h>
#include <cstddef>

// Problem constants (match reference)
static constexpr int Bdim = 32;
static constexpr int Edim = 256;
static constexpr int Cdim = 7;
static constexpr int Ddim = 256;

// native clang vector for nontemporal stores (builtin rejects HIP_vector_type)
typedef float f32x4n __attribute__((ext_vector_type(4)));

// Precomputed fused tables, 103 rows of 256 floats:
// rows   0..52 : cardP = card_table   @ Wc[   0: 256]
// rows  53..61 : heroP = hero_table   @ Wc[ 256: 512]
// rows  62..70 : actP  = acting_table @ Wc[ 512: 768]
// rows  71..80 : numP  = nump_table   @ Wc[ 768:1024]
// rows  81..82 : WsP   = W_scalar     @ Wc[1024:1280]
// rows  83..91 : WbP   = W_bet        @ Wc[1280:1536]
// rows  92..99 : WaP   = W_action     @ Wc[1536:1792]
// row   100   : b_scalar @ Wc[1024:1280]  + b_combine   (folded here)
// row   101   : b_bet    @ Wc[1280:1536]
// row   102   : b_action @ Wc[1536:1792]
// NOTE: rows 100-102 are THREE PARALLEL BLOCKS (round-2 regression was
// fusing them into one block doing 3 serial 256-dots; kernel time ==
// slowest block since all blocks run concurrently).
// g_sums[r]  : row sums of card rows (for LN mean decomposition)
__device__ float g_tabs[103 * Ddim];
__device__ float g_sums[53];

// One block per row (103 blocks x 256 threads). Thread d computes
// g_tabs[r][d] = sum_k src_r[k] * Wc[off + k][d].
// Card rows additionally block-reduce their row sum into g_sums[r].
__global__ __launch_bounds__(256) void precompute_tables(
    const float* __restrict__ card_table,
    const float* __restrict__ hero_table,
    const float* __restrict__ acting_table,
    const float* __restrict__ nump_table,
    const float* __restrict__ W_scalar, const float* __restrict__ b_scalar,
    const float* __restrict__ W_bet,    const float* __restrict__ b_bet,
    const float* __restrict__ W_action, const float* __restrict__ b_action,
    const float* __restrict__ W_combine, const float* __restrict__ b_combine)
{
    const int r = blockIdx.x;
    const int d = threadIdx.x;

    const float* srcp;
    int off;
    if      (r <  53) { srcp = card_table   + (size_t)r        * Ddim; off = 0;    }
    else if (r <  62) { srcp = hero_table   + (size_t)(r - 53) * Ddim; off = 256;  }
    else if (r <  71) { srcp = acting_table + (size_t)(r - 62) * Ddim; off = 512;  }
    else if (r <  81) { srcp = nump_table   + (size_t)(r - 71) * Ddim; off = 768;  }
    else if (r <  83) { srcp = W_scalar     + (size_t)(r - 81) * Ddim; off = 1024; }
    else if (r <  92) { srcp = W_bet        + (size_t)(r - 83) * Ddim; off = 1280; }
    else if (r < 100) { srcp = W_action     + (size_t)(r - 92) * Ddim; off = 1536; }
    else if (r == 100){ srcp = b_scalar;                               off = 1024; }
    else if (r == 101){ srcp = b_bet;                                  off = 1280; }
    else              { srcp = b_action;                               off = 1536; }

    const float* w = W_combine + (size_t)off * Ddim + d;
    float a0 = 0.f, a1 = 0.f, a2 = 0.f, a3 = 0.f;
    #pragma unroll 8
    for (int k = 0; k < 64; ++k) {
        const float s0 = srcp[k      ];
        const float s1 = srcp[k +  64];
        const float s2 = srcp[k + 128];
        const float s3 = srcp[k + 192];
        a0 = fmaf(s0, w[(size_t)(k      ) * Ddim], a0);
        a1 = fmaf(s1, w[(size_t)(k +  64) * Ddim], a1);
        a2 = fmaf(s2, w[(size_t)(k + 128) * Ddim], a2);
        a3 = fmaf(s3, w[(size_t)(k + 192) * Ddim], a3);
    }
    float v = (a0 + a1) + (a2 + a3);
    if (r == 100) v += b_combine[d];          // fold b_combine into row 100
    g_tabs[(size_t)r * Ddim + d] = v;

    if (r < 53) {
        // block-reduce the row sum for the mean decomposition
        float t = v;
        #pragma unroll
        for (int o = 32; o > 0; o >>= 1) t += __shfl_xor(t, o, 64);
        __shared__ float ws4[4];
        if ((threadIdx.x & 63) == 0) ws4[threadIdx.x >> 6] = t;
        __syncthreads();
        if (threadIdx.x == 0) g_sums[r] = (ws4[0] + ws4[1]) + (ws4[2] + ws4[3]);
    }
}

__device__ __forceinline__ float4 ld4(const float* p) {
    return *reinterpret_cast<const float4*>(p);
}
__device__ __forceinline__ void add4(float4& a, const float4 b) {
    a.x += b.x; a.y += b.y; a.z += b.z; a.w += b.w;
}
__device__ __forceinline__ void fma4(float4& a, const float s, const float4 b) {
    a.x = fmaf(s, b.x, a.x);
    a.y = fmaf(s, b.y, a.y);
    a.z = fmaf(s, b.z, a.z);
    a.w = fmaf(s, b.w, a.w);
}

// One wave (64 lanes) per event; lane holds d = 4*lane .. 4*lane+3 as float4.
// LN mean decomposed: mean = (rowsum(card) + sum(ctx))/256, so only the
// sum-of-squares needs a per-card butterfly (6 shuffles instead of 12),
// and the epilogue is folded to o = h*A + B per element.
__global__ __launch_bounds__(256) void event_embed(
    const int* __restrict__ card_ids,
    const int* __restrict__ hero_pos,
    const int* __restrict__ acting_pos,
    const int* __restrict__ num_players,
    const int* __restrict__ seq_lengths,
    const float* __restrict__ scalars,
    const float* __restrict__ bets,
    const float* __restrict__ action,
    const float* __restrict__ source_table,
    const float* __restrict__ ln_gamma,
    const float* __restrict__ ln_beta,
    float* __restrict__ out_emb,
    float* __restrict__ out_mask)
{
    const int wave = threadIdx.x >> 6;
    const int lane = threadIdx.x & 63;
    const int g = (blockIdx.x << 2) + wave;   // event index in [0, B*E)
    const int b = g >> 8;                     // E = 256
    const int e = g & 255;
    const int d0 = lane << 2;

    const float* cardP = g_tabs;
    const float* heroP = cardP + 53 * Ddim;
    const float* actP  = heroP +  9 * Ddim;
    const float* numP  = actP  +  9 * Ddim;
    const float* WsP   = numP  + 10 * Ddim;
    const float* WbP   = WsP   +  2 * Ddim;
    const float* WaP   = WbP   +  9 * Ddim;
    const float* bS    = WaP   +  8 * Ddim;   // row 100 (incl. b_combine)
    const float* bB    = bS    +      Ddim;   // row 101
    const float* bA    = bB    +      Ddim;   // row 102

    const float maskf = (e < seq_lengths[b]) ? 1.0f : 0.0f;

    // ---- context vector shared by the event's 7 cards ----
    float4 ctx = ld4(bS + d0);
    add4(ctx, ld4(bB + d0));
    add4(ctx, ld4(bA + d0));
    add4(ctx, ld4(heroP + (size_t)hero_pos[g]    * Ddim + d0));
    add4(ctx, ld4(actP  + (size_t)acting_pos[g]  * Ddim + d0));
    add4(ctx, ld4(numP  + (size_t)num_players[g] * Ddim + d0));
    const float2 sc = *reinterpret_cast<const float2*>(scalars + (size_t)g * 2);
    fma4(ctx, sc.x, ld4(WsP + d0));
    fma4(ctx, sc.y, ld4(WsP + Ddim + d0));
    #pragma unroll
    for (int j = 0; j < 9; ++j)
        fma4(ctx, bets[(size_t)g * 9 + j], ld4(WbP + j * Ddim + d0));
    const float4 ac0 = ld4(action + (size_t)g * 8);
    const float4 ac1 = ld4(action + (size_t)g * 8 + 4);
    fma4(ctx, ac0.x, ld4(WaP + 0 * Ddim + d0));
    fma4(ctx, ac0.y, ld4(WaP + 1 * Ddim + d0));
    fma4(ctx, ac0.z, ld4(WaP + 2 * Ddim + d0));
    fma4(ctx, ac0.w, ld4(WaP + 3 * Ddim + d0));
    fma4(ctx, ac1.x, ld4(WaP + 4 * Ddim + d0));
    fma4(ctx, ac1.y, ld4(WaP + 5 * Ddim + d0));
    fma4(ctx, ac1.z, ld4(WaP + 6 * Ddim + d0));
    fma4(ctx, ac1.w, ld4(WaP + 7 * Ddim + d0));

    // ---- one reduction for sum(ctx) (feeds mean of every card) ----
    float cs = (ctx.x + ctx.y) + (ctx.z + ctx.w);
    #pragma unroll
    for (int o = 32; o > 0; o >>= 1) cs += __shfl_xor(cs, o, 64);

    const float4 gam = ld4(ln_gamma + d0);
    const float4 bta = ld4(ln_beta + d0);
    const float4 s0v = ld4(source_table + d0);          // source id 0 (cards 0..4)
    const float4 s1v = ld4(source_table + Ddim + d0);   // source id 1 (cards 5..6)
    // (beta + source) * mask, hoisted out of the card loop
    float4 svb0, svb1;
    svb0.x = (bta.x + s0v.x) * maskf; svb0.y = (bta.y + s0v.y) * maskf;
    svb0.z = (bta.z + s0v.z) * maskf; svb0.w = (bta.w + s0v.w) * maskf;
    svb1.x = (bta.x + s1v.x) * maskf; svb1.y = (bta.y + s1v.y) * maskf;
    svb1.z = (bta.z + s1v.z) * maskf; svb1.w = (bta.w + s1v.w) * maskf;

    #pragma unroll
    for (int c = 0; c < Cdim; ++c) {
        const int cid = card_ids[(size_t)g * Cdim + c];
        const float Sc = g_sums[cid];                    // precomputed row sum
        float4 h = ld4(cardP + (size_t)cid * Ddim + d0);
        add4(h, ctx);

        // only sum-of-squares needs the butterfly now
        float sq = h.x * h.x;
        sq = fmaf(h.y, h.y, sq);
        sq = fmaf(h.z, h.z, sq);
        sq = fmaf(h.w, h.w, sq);
        #pragma unroll
        for (int o = 32; o > 0; o >>= 1) sq += __shfl_xor(sq, o, 64);

        const float mean = (Sc + cs) * (1.0f / 256.0f);
        const float var  = fmaf(-mean, mean, sq * (1.0f / 256.0f));
        const float im   = rsqrtf(var + 1e-5f) * maskf;  // mask folded in

        // o = h*A + B,  A = im*gamma,  B = svb*mask - mean*A
        const float4 svb = (c < 5) ? svb0 : svb1;
        float4 A, Bv, o;
        A.x = im * gam.x; A.y = im * gam.y; A.z = im * gam.z; A.w = im * gam.w;
        Bv.x = fmaf(-mean, A.x, svb.x); Bv.y = fmaf(-mean, A.y, svb.y);
        Bv.z = fmaf(-mean, A.z, svb.z); Bv.w = fmaf(-mean, A.w, svb.w);
        o.x = fmaf(h.x, A.x, Bv.x); o.y = fmaf(h.y, A.y, Bv.y);
        o.z = fmaf(h.z, A.z, Bv.z); o.w = fmaf(h.w, A.w, Bv.w);
        // streaming, write-once output: nontemporal to spare L2 for g_tabs.
        // builtin requires a native clang vector type -> bitcast via f32x4n.
        __builtin_nontemporal_store(*reinterpret_cast<const f32x4n*>(&o),
            reinterpret_cast<f32x4n*>(out_emb + ((size_t)g * Cdim + c) * Ddim + d0));
    }

    if (lane < Cdim)
        out_mask[(size_t)g * Cdim + lane] = maskf;
}

extern "C" void kernel_launch(void* const* d_in, const int* in_sizes, int n_in,
                              void* d_out, int out_size, void* d_ws, size_t ws_size,
                              hipStream_t stream)
{
    (void)in_sizes; (void)n_in; (void)d_ws; (void)ws_size; (void)out_size;

    const int*   card_ids    = (const int*)d_in[0];
    const int*   hero_pos    = (const int*)d_in[1];
    const int*   acting_pos  = (const int*)d_in[2];
    const int*   num_players = (const int*)d_in[3];
    const int*   seq_lengths = (const int*)d_in[4];
    const float* scalars     = (const float*)d_in[5];
    const float* bets        = (const float*)d_in[6];
    const float* action      = (const float*)d_in[7];
    const float* card_table  = (const float*)d_in[8];
    const float* source_tab  = (const float*)d_in[9];
    const float* hero_table  = (const float*)d_in[10];
    const float* acting_tab  = (const float*)d_in[11];
    const float* nump_table  = (const float*)d_in[12];
    const float* W_scalar    = (const float*)d_in[13];
    const float* b_scalar    = (const float*)d_in[14];
    const float* W_bet       = (const float*)d_in[15];
    const float* b_bet       = (const float*)d_in[16];
    const float* W_action    = (const float*)d_in[17];
    const float* b_action    = (const float*)d_in[18];
    const float* W_combine   = (const float*)d_in[19];
    const float* b_combine   = (const float*)d_in[20];
    const float* ln_gamma    = (const float*)d_in[21];
    const float* ln_beta     = (const float*)d_in[22];

    float* out_emb  = (float*)d_out;
    float* out_mask = out_emb + (size_t)Bdim * Edim * Cdim * Ddim;

    hipLaunchKernelGGL(precompute_tables, dim3(103), dim3(256), 0, stream,
                       card_table, hero_table, acting_tab, nump_table,
                       W_scalar, b_scalar, W_bet, b_bet, W_action, b_action,
                       W_combine, b_combine);

    const int nEvents = Bdim * Edim;             // 8192
    hipLaunchKernelGGL(event_embed, dim3(nEvents / 4), dim3(256), 0, stream,
                       card_ids, hero_pos, acting_pos, num_players, seq_lengths,
                       scalars, bets, action, source_tab,
                       ln_gamma, ln_beta, out_emb, out_mask);
}